// Round 2
// baseline (342.195 us; speedup 1.0000x reference)
//
#include <hip/hip_runtime.h>
#include <hip/hip_bf16.h>

#define B_N 4096
#define L_K 128

typedef __bf16 bf16x8 __attribute__((ext_vector_type(8)));
typedef float  f32x4  __attribute__((ext_vector_type(4)));

// ---------------------------------------------------------------------------
// prep: labels f32 -> bf16 (ws), and inv[i] = 1/sqrt(||labels_i||^2 + 128)
// one wave per row (128 elems = 2 per lane)
// ---------------------------------------------------------------------------
__global__ __launch_bounds__(256) void prep_kernel(const float* __restrict__ labels,
                                                   unsigned short* __restrict__ lb,
                                                   float* __restrict__ inv) {
    const int wave = blockIdx.x * 4 + (threadIdx.x >> 6);
    const int lane = threadIdx.x & 63;
    const int row  = wave;                      // grid = 4096/4 blocks -> rows 0..4095

    const float x0 = labels[row * L_K + lane];
    const float x1 = labels[row * L_K + 64 + lane];

    __hip_bfloat16 h0 = __float2bfloat16(x0);
    __hip_bfloat16 h1 = __float2bfloat16(x1);
    lb[row * L_K + lane]      = *reinterpret_cast<unsigned short*>(&h0);
    lb[row * L_K + 64 + lane] = *reinterpret_cast<unsigned short*>(&h1);

    float s = x0 * x0 + x1 * x1;
    #pragma unroll
    for (int m = 32; m >= 1; m >>= 1) s += __shfl_xor(s, m);
    if (lane == 0) inv[row] = 1.0f / sqrtf(s + 128.0f);
}

// ---------------------------------------------------------------------------
// main: per block (256 thr = 4 waves) one 64x64 tile of the 4096x4096 matrix.
//  - wave w: 16x64 strip of labels@labels^T via 16 mfma_f32_16x16x32_bf16
//  - m = floor((dot+128)*inv_i*inv_j) -> LDS
//  - all threads: float4-vectorized smooth-L1 over outputs0/outputs1 vs m
//  - wave reduce -> atomicAdd(double)
// ---------------------------------------------------------------------------
__global__ __launch_bounds__(256) void main_kernel(const float* __restrict__ o0,
                                                   const float* __restrict__ o1,
                                                   const unsigned short* __restrict__ lb,
                                                   const float* __restrict__ inv,
                                                   double* __restrict__ acc_out) {
    __shared__ __align__(16) float m_lds[64][64];

    const int ti = blockIdx.x >> 6;      // row tile (64 tiles of 64)
    const int tj = blockIdx.x & 63;      // col tile
    const int w  = threadIdx.x >> 6;     // wave id 0..3
    const int l  = threadIdx.x & 63;     // lane
    const int fr = l & 15;               // fragment row (A) / col (B)
    const int fk = (l >> 4) * 8;         // k sub-offset within 32-chunk

    const int r0 = ti * 64 + w * 16;     // global row base of this wave's strip
    const int c0 = tj * 64;              // global col base of the block tile

    f32x4 acc[4] = {};                   // one 16x16 accum per col-subtile

    #pragma unroll
    for (int kk = 0; kk < 4; ++kk) {     // K = 128 = 4 * 32
        const bf16x8 a = *reinterpret_cast<const bf16x8*>(
            lb + (size_t)(r0 + fr) * L_K + kk * 32 + fk);
        #pragma unroll
        for (int ct = 0; ct < 4; ++ct) {
            const bf16x8 b = *reinterpret_cast<const bf16x8*>(
                lb + (size_t)(c0 + ct * 16 + fr) * L_K + kk * 32 + fk);
            acc[ct] = __builtin_amdgcn_mfma_f32_16x16x32_bf16(a, b, acc[ct], 0, 0, 0);
        }
    }

    // epilogue: multi_labels tile into LDS
    // C/D layout (verified): col = lane&15, row = (lane>>4)*4 + reg
    float invi[4];
    #pragma unroll
    for (int r = 0; r < 4; ++r) invi[r] = inv[r0 + (l >> 4) * 4 + r];
    float invj[4];
    #pragma unroll
    for (int ct = 0; ct < 4; ++ct) invj[ct] = inv[c0 + ct * 16 + (l & 15)];

    #pragma unroll
    for (int ct = 0; ct < 4; ++ct) {
        #pragma unroll
        for (int r = 0; r < 4; ++r) {
            const int li = w * 16 + (l >> 4) * 4 + r;   // local row in 64-tile
            const int lj = ct * 16 + (l & 15);          // local col
            const float ratio = (acc[ct][r] + 128.0f) * invi[r] * invj[ct];
            m_lds[li][lj] = floorf(ratio);
        }
    }
    __syncthreads();

    // fused smooth-L1 over both output matrices, float4 loads (16 B/lane)
    float lsum = 0.0f;
    #pragma unroll
    for (int v = 0; v < 4; ++v) {
        const int idx = v * 256 + threadIdx.x;          // 0..1023 float4s
        const int row = idx >> 4;                       // 0..63
        const int c4  = (idx & 15) * 4;                 // 0,4,..,60
        const size_t goff = (size_t)(ti * 64 + row) * B_N + (size_t)(tj * 64 + c4);
        const float4 a0 = *reinterpret_cast<const float4*>(o0 + goff);
        const float4 a1 = *reinterpret_cast<const float4*>(o1 + goff);
        const float4 mm = *reinterpret_cast<const float4*>(&m_lds[row][c4]);

        const float mv[4] = {mm.x, mm.y, mm.z, mm.w};
        const float p0[4] = {a0.x, a0.y, a0.z, a0.w};
        const float p1[4] = {a1.x, a1.y, a1.z, a1.w};
        #pragma unroll
        for (int q = 0; q < 4; ++q) {
            float d0 = fabsf(p0[q] - mv[q]);
            float d1 = fabsf(p1[q] - mv[q]);
            lsum += (d0 < 1.0f) ? 0.5f * d0 * d0 : d0 - 0.5f;
            lsum += (d1 < 1.0f) ? 0.5f * d1 * d1 : d1 - 0.5f;
        }
    }

    #pragma unroll
    for (int m = 32; m >= 1; m >>= 1) lsum += __shfl_xor(lsum, m);
    if (l == 0) atomicAdd(acc_out, (double)lsum);
}

// ---------------------------------------------------------------------------
// finalize: loss = (sum0+sum1) / (2 * B*B)
// ---------------------------------------------------------------------------
__global__ void fin_kernel(const double* __restrict__ acc, float* __restrict__ out) {
    out[0] = (float)(acc[0] / (2.0 * (double)B_N * (double)B_N));
}

extern "C" void kernel_launch(void* const* d_in, const int* in_sizes, int n_in,
                              void* d_out, int out_size, void* d_ws, size_t ws_size,
                              hipStream_t stream) {
    const float* o0     = (const float*)d_in[0];
    const float* o1     = (const float*)d_in[1];
    const float* labels = (const float*)d_in[2];
    float* out = (float*)d_out;

    char* ws = (char*)d_ws;
    unsigned short* lb = (unsigned short*)ws;                       // 1 MB bf16 labels
    float* inv = (float*)(ws + (size_t)B_N * L_K * 2);              // 16 KB
    double* acc = (double*)(ws + (size_t)B_N * L_K * 2 + B_N * 4);  // 8 B accumulator

    hipMemsetAsync(acc, 0, sizeof(double), stream);
    prep_kernel<<<B_N / 4, 256, 0, stream>>>(labels, lb, inv);
    main_kernel<<<(B_N / 64) * (B_N / 64), 256, 0, stream>>>(o0, o1, lb, inv, acc);
    fin_kernel<<<1, 1, 0, stream>>>(acc, out);
}

// Round 3
// 184.335 us; speedup vs baseline: 1.8564x; 1.8564x over previous
//
#include <hip/hip_runtime.h>
#include <hip/hip_bf16.h>

#define B_N 4096
#define L_K 128
#define NBLK ((B_N / 64) * (B_N / 64))   // 4096 blocks

typedef __bf16 bf16x8 __attribute__((ext_vector_type(8)));
typedef float  f32x4  __attribute__((ext_vector_type(4)));

// ---------------------------------------------------------------------------
// prep: labels f32 -> bf16 (ws), and inv[i] = 1/sqrt(||labels_i||^2 + 128)
// one wave per row (128 elems = 2 per lane)
// ---------------------------------------------------------------------------
__global__ __launch_bounds__(256) void prep_kernel(const float* __restrict__ labels,
                                                   unsigned short* __restrict__ lb,
                                                   float* __restrict__ inv) {
    const int wave = blockIdx.x * 4 + (threadIdx.x >> 6);
    const int lane = threadIdx.x & 63;
    const int row  = wave;                      // grid = 4096/4 blocks -> rows 0..4095

    const float x0 = labels[row * L_K + lane];
    const float x1 = labels[row * L_K + 64 + lane];

    __hip_bfloat16 h0 = __float2bfloat16(x0);
    __hip_bfloat16 h1 = __float2bfloat16(x1);
    lb[row * L_K + lane]      = *reinterpret_cast<unsigned short*>(&h0);
    lb[row * L_K + 64 + lane] = *reinterpret_cast<unsigned short*>(&h1);

    float s = x0 * x0 + x1 * x1;
    #pragma unroll
    for (int m = 32; m >= 1; m >>= 1) s += __shfl_xor(s, m);
    if (lane == 0) inv[row] = 1.0f / sqrtf(s + 128.0f);
}

// ---------------------------------------------------------------------------
// main: per block (256 thr = 4 waves) one 64x64 tile of the 4096x4096 matrix.
//  - wave w: 16x64 strip of labels@labels^T via 16 mfma_f32_16x16x32_bf16
//  - m = floor((dot+128)*inv_i*inv_j) -> LDS
//  - all threads: float4-vectorized smooth-L1 over outputs0/outputs1 vs m
//  - block reduce -> ONE plain store per block (no atomics: the single-address
//    atomicAdd(double) serialized 65536 ops and cost 200+ us in round 2)
// ---------------------------------------------------------------------------
__global__ __launch_bounds__(256) void main_kernel(const float* __restrict__ o0,
                                                   const float* __restrict__ o1,
                                                   const unsigned short* __restrict__ lb,
                                                   const float* __restrict__ inv,
                                                   float* __restrict__ partials) {
    __shared__ __align__(16) float m_lds[64][64];
    __shared__ float wsum[4];

    const int ti = blockIdx.x >> 6;      // row tile (64 tiles of 64)
    const int tj = blockIdx.x & 63;      // col tile
    const int w  = threadIdx.x >> 6;     // wave id 0..3
    const int l  = threadIdx.x & 63;     // lane
    const int fr = l & 15;               // fragment row (A) / col (B)
    const int fk = (l >> 4) * 8;         // k sub-offset within 32-chunk

    const int r0 = ti * 64 + w * 16;     // global row base of this wave's strip
    const int c0 = tj * 64;              // global col base of the block tile

    f32x4 acc[4] = {};                   // one 16x16 accum per col-subtile

    #pragma unroll
    for (int kk = 0; kk < 4; ++kk) {     // K = 128 = 4 * 32
        const bf16x8 a = *reinterpret_cast<const bf16x8*>(
            lb + (size_t)(r0 + fr) * L_K + kk * 32 + fk);
        #pragma unroll
        for (int ct = 0; ct < 4; ++ct) {
            const bf16x8 b = *reinterpret_cast<const bf16x8*>(
                lb + (size_t)(c0 + ct * 16 + fr) * L_K + kk * 32 + fk);
            acc[ct] = __builtin_amdgcn_mfma_f32_16x16x32_bf16(a, b, acc[ct], 0, 0, 0);
        }
    }

    // epilogue: multi_labels tile into LDS
    // C/D layout (verified): col = lane&15, row = (lane>>4)*4 + reg
    float invi[4];
    #pragma unroll
    for (int r = 0; r < 4; ++r) invi[r] = inv[r0 + (l >> 4) * 4 + r];
    float invj[4];
    #pragma unroll
    for (int ct = 0; ct < 4; ++ct) invj[ct] = inv[c0 + ct * 16 + (l & 15)];

    #pragma unroll
    for (int ct = 0; ct < 4; ++ct) {
        #pragma unroll
        for (int r = 0; r < 4; ++r) {
            const int li = w * 16 + (l >> 4) * 4 + r;   // local row in 64-tile
            const int lj = ct * 16 + (l & 15);          // local col
            const float ratio = (acc[ct][r] + 128.0f) * invi[r] * invj[ct];
            m_lds[li][lj] = floorf(ratio);
        }
    }
    __syncthreads();

    // fused smooth-L1 over both output matrices, float4 loads (16 B/lane)
    float lsum = 0.0f;
    #pragma unroll
    for (int v = 0; v < 4; ++v) {
        const int idx = v * 256 + threadIdx.x;          // 0..1023 float4s
        const int row = idx >> 4;                       // 0..63
        const int c4  = (idx & 15) * 4;                 // 0,4,..,60
        const size_t goff = (size_t)(ti * 64 + row) * B_N + (size_t)(tj * 64 + c4);
        const float4 a0 = *reinterpret_cast<const float4*>(o0 + goff);
        const float4 a1 = *reinterpret_cast<const float4*>(o1 + goff);
        const float4 mm = *reinterpret_cast<const float4*>(&m_lds[row][c4]);

        const float mv[4] = {mm.x, mm.y, mm.z, mm.w};
        const float p0[4] = {a0.x, a0.y, a0.z, a0.w};
        const float p1[4] = {a1.x, a1.y, a1.z, a1.w};
        #pragma unroll
        for (int q = 0; q < 4; ++q) {
            float d0 = fabsf(p0[q] - mv[q]);
            float d1 = fabsf(p1[q] - mv[q]);
            lsum += (d0 < 1.0f) ? 0.5f * d0 * d0 : d0 - 0.5f;
            lsum += (d1 < 1.0f) ? 0.5f * d1 * d1 : d1 - 0.5f;
        }
    }

    #pragma unroll
    for (int m = 32; m >= 1; m >>= 1) lsum += __shfl_xor(lsum, m);
    if (l == 0) wsum[w] = lsum;
    __syncthreads();
    if (threadIdx.x == 0)
        partials[blockIdx.x] = wsum[0] + wsum[1] + wsum[2] + wsum[3];
}

// ---------------------------------------------------------------------------
// finalize: one block, reduce 4096 partials in double, scale
// ---------------------------------------------------------------------------
__global__ __launch_bounds__(1024) void fin_kernel(const float* __restrict__ partials,
                                                   float* __restrict__ out) {
    __shared__ double wred[16];
    double s = 0.0;
    for (int i = threadIdx.x; i < NBLK; i += 1024) s += (double)partials[i];
    #pragma unroll
    for (int m = 32; m >= 1; m >>= 1) s += __shfl_xor(s, m);
    const int l = threadIdx.x & 63, w = threadIdx.x >> 6;
    if (l == 0) wred[w] = s;
    __syncthreads();
    if (threadIdx.x == 0) {
        double t = 0.0;
        #pragma unroll
        for (int i = 0; i < 16; ++i) t += wred[i];
        out[0] = (float)(t / (2.0 * (double)B_N * (double)B_N));
    }
}

extern "C" void kernel_launch(void* const* d_in, const int* in_sizes, int n_in,
                              void* d_out, int out_size, void* d_ws, size_t ws_size,
                              hipStream_t stream) {
    const float* o0     = (const float*)d_in[0];
    const float* o1     = (const float*)d_in[1];
    const float* labels = (const float*)d_in[2];
    float* out = (float*)d_out;

    char* ws = (char*)d_ws;
    unsigned short* lb = (unsigned short*)ws;                        // 1 MB bf16 labels
    float* inv      = (float*)(ws + (size_t)B_N * L_K * 2);          // 16 KB
    float* partials = (float*)(ws + (size_t)B_N * L_K * 2 + B_N * 4);// 16 KB (4096 floats)

    prep_kernel<<<B_N / 4, 256, 0, stream>>>(labels, lb, inv);
    main_kernel<<<NBLK, 256, 0, stream>>>(o0, o1, lb, inv, partials);
    fin_kernel<<<1, 1024, 0, stream>>>(partials, out);
}

// Round 4
// 165.834 us; speedup vs baseline: 2.0635x; 1.1116x over previous
//
#include <hip/hip_runtime.h>
#include <hip/hip_bf16.h>

#define B_N 4096
#define L_K 128
#define NBLK ((B_N / 64) * (B_N / 64))   // 4096 blocks

typedef __bf16 bf16x8 __attribute__((ext_vector_type(8)));
typedef float  f32x4  __attribute__((ext_vector_type(4)));

#define GPTR(p) (const __attribute__((address_space(1))) void*)(p)
#define LPTR(p) (__attribute__((address_space(3))) void*)(p)

// ---------------------------------------------------------------------------
// prep: labels f32 -> bf16 (ws), and inv[i] = 1/sqrt(||labels_i||^2 + 128)
// ---------------------------------------------------------------------------
__global__ __launch_bounds__(256) void prep_kernel(const float* __restrict__ labels,
                                                   unsigned short* __restrict__ lb,
                                                   float* __restrict__ inv) {
    const int wave = blockIdx.x * 4 + (threadIdx.x >> 6);
    const int lane = threadIdx.x & 63;
    const int row  = wave;

    const float x0 = labels[row * L_K + lane];
    const float x1 = labels[row * L_K + 64 + lane];

    __hip_bfloat16 h0 = __float2bfloat16(x0);
    __hip_bfloat16 h1 = __float2bfloat16(x1);
    lb[row * L_K + lane]      = *reinterpret_cast<unsigned short*>(&h0);
    lb[row * L_K + 64 + lane] = *reinterpret_cast<unsigned short*>(&h1);

    float s = x0 * x0 + x1 * x1;
    #pragma unroll
    for (int m = 32; m >= 1; m >>= 1) s += __shfl_xor(s, m);
    if (lane == 0) inv[row] = 1.0f / sqrtf(s + 128.0f);
}

// ---------------------------------------------------------------------------
// main: 64x64 tile per block (4 waves).
//  Phase 0: async-stage o0/o1 tiles global->LDS via global_load_lds (width 16,
//           zero VGPR cost) — issued FIRST so HBM latency hides under gram.
//  Phase 1: gram via 16x mfma_f32_16x16x32_bf16 per wave (lb is L2-resident),
//           m = floor((dot+128)*inv_i*inv_j) -> m_lds.
//  sync (compiler's vmcnt(0) drain = staged tiles have arrived)
//  Phase 2: smooth-L1 entirely out of LDS, block reduce, one store.
// Round-3 lesson: VGPR=24 => ~2 loads in flight/wave => latency-bound 77us.
// ---------------------------------------------------------------------------
__global__ __launch_bounds__(256) void main_kernel(const float* __restrict__ o0,
                                                   const float* __restrict__ o1,
                                                   const unsigned short* __restrict__ lb,
                                                   const float* __restrict__ inv,
                                                   float* __restrict__ partials) {
    __shared__ __align__(16) float o0t[64 * 64];     // 16 KB
    __shared__ __align__(16) float o1t[64 * 64];     // 16 KB
    __shared__ __align__(16) float m_lds[64][64];    // 16 KB
    __shared__ float wsum[4];

    const int ti = blockIdx.x >> 6;
    const int tj = blockIdx.x & 63;
    const int w  = threadIdx.x >> 6;
    const int l  = threadIdx.x & 63;

    // ---- Phase 0: stage 32 KB of outputs to LDS, async, before anything ----
    {
        const int sr = l >> 4;            // 0..3 sub-row within 4-row group
        const int sc = (l & 15) * 4;      // float col, 16B per lane
        #pragma unroll
        for (int q2 = 0; q2 < 4; ++q2) {
            const int q   = w * 4 + q2;   // 0..15, wave-uniform
            const int row = q * 4 + sr;
            const size_t goff = (size_t)(ti * 64 + row) * B_N + (size_t)(tj * 64 + sc);
            __builtin_amdgcn_global_load_lds(GPTR(o0 + goff), LPTR(&o0t[q * 256]), 16, 0, 0);
            __builtin_amdgcn_global_load_lds(GPTR(o1 + goff), LPTR(&o1t[q * 256]), 16, 0, 0);
        }
    }

    // ---- Phase 1: gram + m tile ----
    const int fr = l & 15;
    const int fk = (l >> 4) * 8;
    const int r0 = ti * 64 + w * 16;
    const int c0 = tj * 64;

    // inv gathers early (L2-resident, latency hidden under MFMA phase)
    float invi[4];
    #pragma unroll
    for (int r = 0; r < 4; ++r) invi[r] = inv[r0 + (l >> 4) * 4 + r];
    float invj[4];
    #pragma unroll
    for (int ct = 0; ct < 4; ++ct) invj[ct] = inv[c0 + ct * 16 + (l & 15)];

    f32x4 acc[4] = {};
    #pragma unroll
    for (int kk = 0; kk < 4; ++kk) {      // K = 128 = 4 * 32
        const bf16x8 a = *reinterpret_cast<const bf16x8*>(
            lb + (size_t)(r0 + fr) * L_K + kk * 32 + fk);
        #pragma unroll
        for (int ct = 0; ct < 4; ++ct) {
            const bf16x8 b = *reinterpret_cast<const bf16x8*>(
                lb + (size_t)(c0 + ct * 16 + fr) * L_K + kk * 32 + fk);
            acc[ct] = __builtin_amdgcn_mfma_f32_16x16x32_bf16(a, b, acc[ct], 0, 0, 0);
        }
    }

    // C/D layout (verified): col = lane&15, row = (lane>>4)*4 + reg
    #pragma unroll
    for (int ct = 0; ct < 4; ++ct) {
        #pragma unroll
        for (int r = 0; r < 4; ++r) {
            const int li = w * 16 + (l >> 4) * 4 + r;
            const int lj = ct * 16 + (l & 15);
            const float ratio = (acc[ct][r] + 128.0f) * invi[r] * invj[ct];
            m_lds[li][lj] = floorf(ratio);
        }
    }

    __syncthreads();   // waves drain vmcnt(0): staged o-tiles + m_lds all ready

    // ---- Phase 2: smooth-L1 from LDS only ----
    float lsum = 0.0f;
    #pragma unroll
    for (int v = 0; v < 4; ++v) {
        const int idx = v * 256 + threadIdx.x;   // 0..1023 float4s
        const int row = idx >> 4;
        const int c4  = (idx & 15) * 4;
        const f32x4 a0 = *reinterpret_cast<const f32x4*>(&o0t[row * 64 + c4]);
        const f32x4 a1 = *reinterpret_cast<const f32x4*>(&o1t[row * 64 + c4]);
        const f32x4 mm = *reinterpret_cast<const f32x4*>(&m_lds[row][c4]);
        #pragma unroll
        for (int q = 0; q < 4; ++q) {
            float d0 = fabsf(a0[q] - mm[q]);
            float d1 = fabsf(a1[q] - mm[q]);
            lsum += (d0 < 1.0f) ? 0.5f * d0 * d0 : d0 - 0.5f;
            lsum += (d1 < 1.0f) ? 0.5f * d1 * d1 : d1 - 0.5f;
        }
    }

    #pragma unroll
    for (int m = 32; m >= 1; m >>= 1) lsum += __shfl_xor(lsum, m);
    if (l == 0) wsum[w] = lsum;
    __syncthreads();
    if (threadIdx.x == 0)
        partials[blockIdx.x] = wsum[0] + wsum[1] + wsum[2] + wsum[3];
}

// ---------------------------------------------------------------------------
// finalize: one block, reduce 4096 partials in double, scale
// ---------------------------------------------------------------------------
__global__ __launch_bounds__(1024) void fin_kernel(const float* __restrict__ partials,
                                                   float* __restrict__ out) {
    __shared__ double wred[16];
    double s = 0.0;
    for (int i = threadIdx.x; i < NBLK; i += 1024) s += (double)partials[i];
    #pragma unroll
    for (int m = 32; m >= 1; m >>= 1) s += __shfl_xor(s, m);
    const int l = threadIdx.x & 63, w = threadIdx.x >> 6;
    if (l == 0) wred[w] = s;
    __syncthreads();
    if (threadIdx.x == 0) {
        double t = 0.0;
        #pragma unroll
        for (int i = 0; i < 16; ++i) t += wred[i];
        out[0] = (float)(t / (2.0 * (double)B_N * (double)B_N));
    }
}

extern "C" void kernel_launch(void* const* d_in, const int* in_sizes, int n_in,
                              void* d_out, int out_size, void* d_ws, size_t ws_size,
                              hipStream_t stream) {
    const float* o0     = (const float*)d_in[0];
    const float* o1     = (const float*)d_in[1];
    const float* labels = (const float*)d_in[2];
    float* out = (float*)d_out;

    char* ws = (char*)d_ws;
    unsigned short* lb = (unsigned short*)ws;                         // 1 MB bf16 labels
    float* inv      = (float*)(ws + (size_t)B_N * L_K * 2);           // 16 KB
    float* partials = (float*)(ws + (size_t)B_N * L_K * 2 + B_N * 4); // 16 KB

    prep_kernel<<<B_N / 4, 256, 0, stream>>>(labels, lb, inv);
    main_kernel<<<NBLK, 256, 0, stream>>>(o0, o1, lb, inv, partials);
    fin_kernel<<<1, 1024, 0, stream>>>(partials, out);
}